// Round 1
// baseline (1407.867 us; speedup 1.0000x reference)
//
#include <hip/hip_runtime.h>
#include <math.h>

// Problem constants: D fixed by the model; E, N taken from in_sizes at launch.
#define D 256

constexpr int BM = 64, BN = 64, BK = 16;

// ---------------------------------------------------------------------------
// Transpose W_k (D x D) -> WkT so GEMM1's B-reads are coalesced over columns.
__global__ __launch_bounds__(256)
void k_transpose(const float* __restrict__ Wk, float* __restrict__ WkT) {
    int j = blockIdx.x;          // output row
    int i = threadIdx.x;         // output col
    WkT[j * D + i] = Wk[i * D + j];
}

// ---------------------------------------------------------------------------
// GEMM1: wq[N][D] = prev[N][D] @ WkT  (WkT[k][c] = W_k[c][k])
// 64x64 tile, 4x4 micro-tile per thread, BK=16.
__global__ __launch_bounds__(256)
void k_gemm_wq(const float* __restrict__ A, const float* __restrict__ B,
               float* __restrict__ Cout, int Nrows) {
    __shared__ float As[BK][BM + 4];   // [k][m], +4 pad keeps 16B align & breaks conflicts
    __shared__ float Bs[BK][BN];

    int tid  = threadIdx.x;
    int row0 = blockIdx.x * BM;
    int col0 = blockIdx.y * BN;
    int ty = tid >> 4;           // 0..15
    int tx = tid & 15;           // 0..15

    float acc[4][4] = {};

    int ak = tid & 15;           // k within chunk
    int am = tid >> 4;           // m base (0..15), +16*i
    int bc = tid & 63;           // col within tile
    int bk = tid >> 6;           // k base (0..3), +4*i

    for (int kk = 0; kk < D; kk += BK) {
        #pragma unroll
        for (int i = 0; i < 4; i++) {
            int m  = am + i * 16;
            int gr = row0 + m;
            As[ak][m] = (gr < Nrows) ? A[(size_t)gr * D + kk + ak] : 0.f;
        }
        #pragma unroll
        for (int i = 0; i < 4; i++) {
            int k = bk + i * 4;
            Bs[k][bc] = B[(size_t)(kk + k) * D + col0 + bc];
        }
        __syncthreads();
        #pragma unroll
        for (int k = 0; k < BK; k++) {
            float4 a = *(const float4*)&As[k][ty * 4];
            float4 b = *(const float4*)&Bs[k][tx * 4];
            acc[0][0] += a.x * b.x; acc[0][1] += a.x * b.y; acc[0][2] += a.x * b.z; acc[0][3] += a.x * b.w;
            acc[1][0] += a.y * b.x; acc[1][1] += a.y * b.y; acc[1][2] += a.y * b.z; acc[1][3] += a.y * b.w;
            acc[2][0] += a.z * b.x; acc[2][1] += a.z * b.y; acc[2][2] += a.z * b.z; acc[2][3] += a.z * b.w;
            acc[3][0] += a.w * b.x; acc[3][1] += a.w * b.y; acc[3][2] += a.w * b.z; acc[3][3] += a.w * b.w;
        }
        __syncthreads();
    }

    #pragma unroll
    for (int i = 0; i < 4; i++) {
        int row = row0 + ty * 4 + i;
        if (row < Nrows) {
            float4 o = { acc[i][0], acc[i][1], acc[i][2], acc[i][3] };
            *(float4*)&Cout[(size_t)row * D + col0 + tx * 4] = o;
        }
    }
}

// ---------------------------------------------------------------------------
// GEMM2: logits = [prev | comb] @ W_g + b_g ; out = sig(logits)*prev + (1-sig)*comb
__global__ __launch_bounds__(256)
void k_gemm_gate(const float* __restrict__ prev, const float* __restrict__ comb,
                 const float* __restrict__ Wg, const float* __restrict__ bg,
                 float* __restrict__ outp, int Nrows) {
    __shared__ float As[BK][BM + 4];
    __shared__ float Bs[BK][BN];

    int tid  = threadIdx.x;
    int row0 = blockIdx.x * BM;
    int col0 = blockIdx.y * BN;
    int ty = tid >> 4;
    int tx = tid & 15;

    float acc[4][4] = {};

    int ak = tid & 15;
    int am = tid >> 4;
    int bc = tid & 63;
    int bk = tid >> 6;

    for (int kk = 0; kk < 2 * D; kk += BK) {
        const float* Asrc = (kk < D) ? prev : comb;
        int kc = (kk < D) ? kk : (kk - D);
        #pragma unroll
        for (int i = 0; i < 4; i++) {
            int m  = am + i * 16;
            int gr = row0 + m;
            As[ak][m] = (gr < Nrows) ? Asrc[(size_t)gr * D + kc + ak] : 0.f;
        }
        #pragma unroll
        for (int i = 0; i < 4; i++) {
            int k = bk + i * 4;
            Bs[k][bc] = Wg[(size_t)(kk + k) * D + col0 + bc];
        }
        __syncthreads();
        #pragma unroll
        for (int k = 0; k < BK; k++) {
            float4 a = *(const float4*)&As[k][ty * 4];
            float4 b = *(const float4*)&Bs[k][tx * 4];
            acc[0][0] += a.x * b.x; acc[0][1] += a.x * b.y; acc[0][2] += a.x * b.z; acc[0][3] += a.x * b.w;
            acc[1][0] += a.y * b.x; acc[1][1] += a.y * b.y; acc[1][2] += a.y * b.z; acc[1][3] += a.y * b.w;
            acc[2][0] += a.z * b.x; acc[2][1] += a.z * b.y; acc[2][2] += a.z * b.z; acc[2][3] += a.z * b.w;
            acc[3][0] += a.w * b.x; acc[3][1] += a.w * b.y; acc[3][2] += a.w * b.z; acc[3][3] += a.w * b.w;
        }
        __syncthreads();
    }

    float4 bgv = *(const float4*)&bg[col0 + tx * 4];
    #pragma unroll
    for (int i = 0; i < 4; i++) {
        int row = row0 + ty * 4 + i;
        if (row < Nrows) {
            size_t base = (size_t)row * D + col0 + tx * 4;
            float4 p  = *(const float4*)&prev[base];
            float4 cb = *(const float4*)&comb[base];
            float lx = acc[i][0] + bgv.x, ly = acc[i][1] + bgv.y;
            float lz = acc[i][2] + bgv.z, lw = acc[i][3] + bgv.w;
            float gx = 1.f / (1.f + expf(-lx));
            float gy = 1.f / (1.f + expf(-ly));
            float gz = 1.f / (1.f + expf(-lz));
            float gw = 1.f / (1.f + expf(-lw));
            float4 o = { gx * p.x + (1.f - gx) * cb.x,
                         gy * p.y + (1.f - gy) * cb.y,
                         gz * p.z + (1.f - gz) * cb.z,
                         gw * p.w + (1.f - gw) * cb.w };
            *(float4*)&outp[base] = o;
        }
    }
}

// ---------------------------------------------------------------------------
// Counting sort of occurrence ids by node index.
__global__ __launch_bounds__(256)
void k_zero(int* __restrict__ p, int n) {
    int i = blockIdx.x * 256 + threadIdx.x;
    if (i < n) p[i] = 0;
}

__global__ __launch_bounds__(256)
void k_hist(const int* __restrict__ idx, int* __restrict__ counts,
            int* __restrict__ rank, int E_) {
    int e = blockIdx.x * 256 + threadIdx.x;
    if (e < E_) rank[e] = atomicAdd(&counts[idx[e]], 1);
}

__global__ __launch_bounds__(256)
void k_part(const int* __restrict__ counts, int* __restrict__ chunkSums, int Nn) {
    __shared__ int sd[256];
    int base = blockIdx.x * 1024;
    int t = threadIdx.x;
    int s = 0;
    #pragma unroll
    for (int i = 0; i < 4; i++) {
        int g = base + t + i * 256;
        if (g < Nn) s += counts[g];
    }
    sd[t] = s;
    __syncthreads();
    for (int st = 128; st; st >>= 1) {
        if (t < st) sd[t] += sd[t + st];
        __syncthreads();
    }
    if (t == 0) chunkSums[blockIdx.x] = sd[0];
}

// Single-block exclusive scan of chunk sums (handles arbitrary P in 256-tiles).
__global__ __launch_bounds__(256)
void k_top(const int* __restrict__ cs, int* __restrict__ co, int P,
           int* __restrict__ offsets, int Nn, int E_) {
    __shared__ int carry;
    __shared__ int ws[4];
    int t = threadIdx.x, lane = t & 63, w = t >> 6;
    if (t == 0) carry = 0;
    __syncthreads();
    for (int base = 0; base < P; base += 256) {
        int i = base + t;
        int v = (i < P) ? cs[i] : 0;
        int orig = v;
        for (int off = 1; off < 64; off <<= 1) {
            int u = __shfl_up(v, off, 64);
            if (lane >= off) v += u;
        }
        if (lane == 63) ws[w] = v;
        __syncthreads();
        int wex = 0;
        for (int k = 0; k < w; k++) wex += ws[k];
        int incl = v + wex;
        if (i < P) co[i] = carry + incl - orig;
        __syncthreads();
        if (t == 255) carry += incl;
        __syncthreads();
    }
    if (t == 0) offsets[Nn] = E_;
}

// Per-chunk exclusive scan (4 elems/thread) + chunk offset -> global offsets.
__global__ __launch_bounds__(256)
void k_off(const int* __restrict__ counts, const int* __restrict__ chunkOff,
           int* __restrict__ offsets, int Nn) {
    int t = threadIdx.x, lane = t & 63, w = t >> 6;
    int base = blockIdx.x * 1024 + t * 4;
    int c[4]; int ts = 0;
    #pragma unroll
    for (int j = 0; j < 4; j++) {
        int g = base + j;
        c[j] = (g < Nn) ? counts[g] : 0;
        ts += c[j];
    }
    int v = ts;
    for (int off = 1; off < 64; off <<= 1) {
        int u = __shfl_up(v, off, 64);
        if (lane >= off) v += u;
    }
    __shared__ int ws[4];
    if (lane == 63) ws[w] = v;
    __syncthreads();
    int wex = 0;
    for (int k = 0; k < w; k++) wex += ws[k];
    int run = chunkOff[blockIdx.x] + wex + v - ts;
    #pragma unroll
    for (int j = 0; j < 4; j++) {
        int g = base + j;
        if (g < Nn) offsets[g] = run;
        run += c[j];
    }
}

__global__ __launch_bounds__(256)
void k_scatter(const int* __restrict__ idx, const int* __restrict__ rank,
               const int* __restrict__ offsets, int* __restrict__ perm, int E_) {
    int e = blockIdx.x * 256 + threadIdx.x;
    if (e < E_) perm[offsets[idx[e]] + rank[e]] = e;
}

// ---------------------------------------------------------------------------
// One wave per node: online-softmax attention over the node's occurrence list.
// Note: b_k . q[n] is constant within a segment -> cancels in softmax; dropped.
__global__ __launch_bounds__(256)
void k_combine(const float* __restrict__ scat, const float* __restrict__ wq,
               const int* __restrict__ offsets, const int* __restrict__ perm,
               float* __restrict__ comb, int Nnodes) {
    int wave = threadIdx.x >> 6;
    int lane = threadIdx.x & 63;
    int n = blockIdx.x * 4 + wave;
    if (n >= Nnodes) return;

    float4 wqv = *(const float4*)&wq[(size_t)n * D + lane * 4];
    int beg = offsets[n], end = offsets[n + 1];

    float m = -INFINITY, l = 0.f;
    float4 acc = { 0.f, 0.f, 0.f, 0.f };
    const float scale = 0.0625f;   // 1/sqrt(256)

    for (int pos = beg; pos < end; ++pos) {
        int e = perm[pos];
        float4 sv = *(const float4*)&scat[(size_t)e * D + lane * 4];
        float d = sv.x * wqv.x + sv.y * wqv.y + sv.z * wqv.z + sv.w * wqv.w;
        #pragma unroll
        for (int off = 32; off; off >>= 1) d += __shfl_xor(d, off, 64);
        float score = d * scale;
        float nm = fmaxf(m, score);
        float al = expf(m - nm);       // first iter: exp(-inf)=0
        float p  = expf(score - nm);
        l = l * al + p;
        acc.x = acc.x * al + p * sv.x;
        acc.y = acc.y * al + p * sv.y;
        acc.z = acc.z * al + p * sv.z;
        acc.w = acc.w * al + p * sv.w;
        m = nm;
    }
    float inv = 1.f / fmaxf(l, 1e-9f);
    float4 o = { acc.x * inv, acc.y * inv, acc.z * inv, acc.w * inv };
    *(float4*)&comb[(size_t)n * D + lane * 4] = o;
}

// ---------------------------------------------------------------------------
extern "C" void kernel_launch(void* const* d_in, const int* in_sizes, int n_in,
                              void* d_out, int out_size, void* d_ws, size_t ws_size,
                              hipStream_t stream) {
    const float* scat = (const float*)d_in[0];
    const float* prev = (const float*)d_in[1];
    const float* Wk   = (const float*)d_in[2];
    // d_in[3] = b_k: unused — constant shift within a segment cancels in softmax.
    const float* Wg   = (const float*)d_in[4];
    const float* bg   = (const float*)d_in[5];
    const int*   idx  = (const int*)d_in[6];

    const int E_ = in_sizes[6];
    const int Nn = in_sizes[1] / D;

    float* out = (float*)d_out;

    // Workspace carve-up (256B aligned). Total ≈ 2*N*D*4 + 2*E*4 + small ≈ 209 MB.
    char* w = (char*)d_ws;
    auto alloc = [&](size_t bytes) -> char* {
        char* p = w;
        w += (bytes + 255) & ~(size_t)255;
        return p;
    };
    float* wq        = (float*)alloc((size_t)Nn * D * 4);
    float* comb      = (float*)alloc((size_t)Nn * D * 4);
    float* WkT       = (float*)alloc((size_t)D * D * 4);
    int*   counts    = (int*)alloc((size_t)Nn * 4);
    int*   offsets   = (int*)alloc(((size_t)Nn + 1) * 4);
    int    P         = (Nn + 1023) / 1024;
    int*   chunkSums = (int*)alloc((size_t)P * 4);
    int*   chunkOff  = (int*)alloc((size_t)P * 4);
    int*   rank      = (int*)alloc((size_t)E_ * 4);
    int*   perm      = (int*)alloc((size_t)E_ * 4);

    // 1) W_k transpose
    k_transpose<<<D, D, 0, stream>>>(Wk, WkT);

    // 2) wq = prev @ W_k^T
    dim3 g1((Nn + BM - 1) / BM, D / BN);
    k_gemm_wq<<<g1, 256, 0, stream>>>(prev, WkT, wq, Nn);

    // 3) counting sort of occurrences by node
    k_zero<<<(Nn + 255) / 256, 256, 0, stream>>>(counts, Nn);
    int gb = (E_ + 255) / 256;
    k_hist<<<gb, 256, 0, stream>>>(idx, counts, rank, E_);
    k_part<<<P, 256, 0, stream>>>(counts, chunkSums, Nn);
    k_top<<<1, 256, 0, stream>>>(chunkSums, chunkOff, P, offsets, Nn, E_);
    k_off<<<P, 256, 0, stream>>>(counts, chunkOff, offsets, Nn);
    k_scatter<<<gb, 256, 0, stream>>>(idx, rank, offsets, perm, E_);

    // 4) per-node online-softmax attention (single pass over scattered_input)
    k_combine<<<(Nn + 3) / 4, 256, 0, stream>>>(scat, wq, offsets, perm, comb, Nn);

    // 5) gate GEMM + sigmoid lerp epilogue
    k_gemm_gate<<<g1, 256, 0, stream>>>(prev, comb, Wg, bg, out, Nn);
}

// Round 2
// 1011.729 us; speedup vs baseline: 1.3915x; 1.3915x over previous
//
#include <hip/hip_runtime.h>
#include <math.h>

#define D 256

typedef __attribute__((ext_vector_type(8))) short short8;
typedef __attribute__((ext_vector_type(4))) float f32x4;

__device__ inline unsigned short f2bf(float f) {
    unsigned int u = __float_as_uint(f);
    u += 0x7fff + ((u >> 16) & 1);          // RNE
    return (unsigned short)(u >> 16);
}
__device__ inline float bf2f(unsigned short h) {
    return __uint_as_float(((unsigned int)h) << 16);
}

// ---------------------------------------------------------------------------
// fp32 -> bf16 bulk convert (8 elems/thread)
__global__ __launch_bounds__(256)
void k_cvt(const float* __restrict__ in, unsigned short* __restrict__ out, int n8) {
    int i = blockIdx.x * 256 + threadIdx.x;
    if (i >= n8) return;
    const float4* p = (const float4*)(in + (size_t)i * 8);
    float4 a = p[0], b = p[1];
    ushort4 o0 = { f2bf(a.x), f2bf(a.y), f2bf(a.z), f2bf(a.w) };
    ushort4 o1 = { f2bf(b.x), f2bf(b.y), f2bf(b.z), f2bf(b.w) };
    ushort4* q = (ushort4*)(out + (size_t)i * 8);
    q[0] = o0; q[1] = o1;
}

// Wg [2D][D] fp32 -> WgT [D][2D] bf16 (n-major B for the gate GEMM)
__global__ __launch_bounds__(256)
void k_cvt_wg(const float* __restrict__ Wg, unsigned short* __restrict__ WgT) {
    int r = blockIdx.x;            // 0..511 (k)
    int c = threadIdx.x;           // 0..255 (n)
    WgT[(size_t)c * (2 * D) + r] = f2bf(Wg[(size_t)r * D + c]);
}

// ---------------------------------------------------------------------------
// MFMA GEMM: C[M][256] = A[M][K] @ B[K][256], A bf16 (A0 | A1 halves for gate),
// B staged n-major: Bn[n][k]. Block: 64 rows x 256 cols, 4 waves, K-step 32.
// GATE=false: store bf16 wq. GATE=true: gate epilogue -> fp32 out.
template <int K, bool GATE>
__global__ __launch_bounds__(256)
void k_mfma_gemm(const unsigned short* __restrict__ A0,
                 const unsigned short* __restrict__ A1,
                 const unsigned short* __restrict__ Bn,
                 const float* __restrict__ bg,
                 const float* __restrict__ prevf,
                 unsigned short* __restrict__ wq_out,
                 float* __restrict__ outp,
                 int Nrows) {
    __shared__ unsigned short As[64 * 32];    // [row][k] 4KB
    __shared__ unsigned short Bs[256 * 32];   // [n][k] 16KB

    int tid  = threadIdx.x;
    int wave = tid >> 6;
    int lane = tid & 63;
    int lcol = lane & 15;
    int quad = lane >> 4;
    int row0 = blockIdx.x * 64;

    f32x4 acc[4][4];
    #pragma unroll
    for (int i = 0; i < 4; i++)
        #pragma unroll
        for (int j = 0; j < 4; j++) acc[i][j] = (f32x4){0.f, 0.f, 0.f, 0.f};

    int arow = tid >> 2, ako = (tid & 3) * 8;
    int grow = row0 + arow;

    for (int kk = 0; kk < K; kk += 32) {
        const unsigned short* Asrc = A0;
        int kc = kk;
        if (GATE && kk >= 256) { Asrc = A1; kc = kk - 256; }

        uint4 av = make_uint4(0u, 0u, 0u, 0u);
        if (grow < Nrows) av = *(const uint4*)&Asrc[(size_t)grow * D + kc + ako];
        *(uint4*)&As[arow * 32 + ako] = av;

        #pragma unroll
        for (int i = 0; i < 4; i++) {
            int c = tid + i * 256;
            int brow = c >> 2, bko = (c & 3) * 8;
            *(uint4*)&Bs[brow * 32 + bko] =
                *(const uint4*)&Bn[(size_t)brow * K + kk + bko];
        }
        __syncthreads();

        short8 a[4], b[4];
        #pragma unroll
        for (int mf = 0; mf < 4; mf++)
            a[mf] = *(const short8*)&As[(mf * 16 + lcol) * 32 + quad * 8];
        #pragma unroll
        for (int nf = 0; nf < 4; nf++)
            b[nf] = *(const short8*)&Bs[(wave * 64 + nf * 16 + lcol) * 32 + quad * 8];
        #pragma unroll
        for (int mf = 0; mf < 4; mf++)
            #pragma unroll
            for (int nf = 0; nf < 4; nf++)
                acc[mf][nf] = __builtin_amdgcn_mfma_f32_16x16x32_bf16(
                    a[mf], b[nf], acc[mf][nf], 0, 0, 0);
        __syncthreads();
    }

    if (!GATE) {
        #pragma unroll
        for (int mf = 0; mf < 4; mf++) {
            #pragma unroll
            for (int nf = 0; nf < 4; nf++) {
                int col = wave * 64 + nf * 16 + lcol;
                #pragma unroll
                for (int r = 0; r < 4; r++) {
                    int gr = row0 + mf * 16 + quad * 4 + r;
                    if (gr < Nrows)
                        wq_out[(size_t)gr * D + col] = f2bf(acc[mf][nf][r]);
                }
            }
        }
    } else {
        float bgv[4];
        #pragma unroll
        for (int nf = 0; nf < 4; nf++) bgv[nf] = bg[wave * 64 + nf * 16 + lcol];
        #pragma unroll
        for (int mf = 0; mf < 4; mf++) {
            #pragma unroll
            for (int nf = 0; nf < 4; nf++) {
                int col = wave * 64 + nf * 16 + lcol;
                #pragma unroll
                for (int r = 0; r < 4; r++) {
                    int gr = row0 + mf * 16 + quad * 4 + r;
                    if (gr < Nrows) {
                        size_t o = (size_t)gr * D + col;
                        float logit = acc[mf][nf][r] + bgv[nf];
                        float g = 1.f / (1.f + __expf(-logit));
                        float cb = bf2f(A1[o]);
                        outp[o] = g * prevf[o] + (1.f - g) * cb;
                    }
                }
            }
        }
    }
}

// ---------------------------------------------------------------------------
// Counting sort of occurrence ids by node index.
__global__ __launch_bounds__(256)
void k_zero(int* __restrict__ p, int n) {
    int i = blockIdx.x * 256 + threadIdx.x;
    if (i < n) p[i] = 0;
}

__global__ __launch_bounds__(256)
void k_hist(const int* __restrict__ idx, int* __restrict__ counts,
            int* __restrict__ rank, int E_) {
    int e = blockIdx.x * 256 + threadIdx.x;
    if (e < E_) rank[e] = atomicAdd(&counts[idx[e]], 1);
}

__global__ __launch_bounds__(256)
void k_part(const int* __restrict__ counts, int* __restrict__ chunkSums, int Nn) {
    __shared__ int sd[256];
    int base = blockIdx.x * 1024;
    int t = threadIdx.x;
    int s = 0;
    #pragma unroll
    for (int i = 0; i < 4; i++) {
        int g = base + t + i * 256;
        if (g < Nn) s += counts[g];
    }
    sd[t] = s;
    __syncthreads();
    for (int st = 128; st; st >>= 1) {
        if (t < st) sd[t] += sd[t + st];
        __syncthreads();
    }
    if (t == 0) chunkSums[blockIdx.x] = sd[0];
}

__global__ __launch_bounds__(256)
void k_top(const int* __restrict__ cs, int* __restrict__ co, int P,
           int* __restrict__ offsets, int Nn, int E_) {
    __shared__ int carry;
    __shared__ int ws[4];
    int t = threadIdx.x, lane = t & 63, w = t >> 6;
    if (t == 0) carry = 0;
    __syncthreads();
    for (int base = 0; base < P; base += 256) {
        int i = base + t;
        int v = (i < P) ? cs[i] : 0;
        int orig = v;
        for (int off = 1; off < 64; off <<= 1) {
            int u = __shfl_up(v, off, 64);
            if (lane >= off) v += u;
        }
        if (lane == 63) ws[w] = v;
        __syncthreads();
        int wex = 0;
        for (int k = 0; k < w; k++) wex += ws[k];
        int incl = v + wex;
        if (i < P) co[i] = carry + incl - orig;
        __syncthreads();
        if (t == 255) carry += incl;
        __syncthreads();
    }
    if (t == 0) offsets[Nn] = E_;
}

__global__ __launch_bounds__(256)
void k_off(const int* __restrict__ counts, const int* __restrict__ chunkOff,
           int* __restrict__ offsets, int Nn) {
    int t = threadIdx.x, lane = t & 63, w = t >> 6;
    int base = blockIdx.x * 1024 + t * 4;
    int c[4]; int ts = 0;
    #pragma unroll
    for (int j = 0; j < 4; j++) {
        int g = base + j;
        c[j] = (g < Nn) ? counts[g] : 0;
        ts += c[j];
    }
    int v = ts;
    for (int off = 1; off < 64; off <<= 1) {
        int u = __shfl_up(v, off, 64);
        if (lane >= off) v += u;
    }
    __shared__ int ws[4];
    if (lane == 63) ws[w] = v;
    __syncthreads();
    int wex = 0;
    for (int k = 0; k < w; k++) wex += ws[k];
    int run = chunkOff[blockIdx.x] + wex + v - ts;
    #pragma unroll
    for (int j = 0; j < 4; j++) {
        int g = base + j;
        if (g < Nn) offsets[g] = run;
        run += c[j];
    }
}

__global__ __launch_bounds__(256)
void k_scatter(const int* __restrict__ idx, const int* __restrict__ rank,
               const int* __restrict__ offsets, int* __restrict__ perm, int E_) {
    int e = blockIdx.x * 256 + threadIdx.x;
    if (e < E_) perm[offsets[idx[e]] + rank[e]] = e;
}

// ---------------------------------------------------------------------------
// One wave per node: online-softmax attention; next-row load pipelined across
// the reduce/exp chain. wq in bf16 (L3-resident gather); comb stored bf16.
__global__ __launch_bounds__(256)
void k_combine(const float* __restrict__ scat, const unsigned short* __restrict__ wq,
               const int* __restrict__ offsets, const int* __restrict__ perm,
               unsigned short* __restrict__ comb, int Nnodes) {
    int wave = threadIdx.x >> 6;
    int lane = threadIdx.x & 63;
    int n = blockIdx.x * 4 + wave;
    if (n >= Nnodes) return;

    ushort4 wu = *(const ushort4*)&wq[(size_t)n * D + lane * 4];
    float4 wqv = { bf2f(wu.x), bf2f(wu.y), bf2f(wu.z), bf2f(wu.w) };
    int beg = offsets[n], end = offsets[n + 1];

    float m = -INFINITY, l = 0.f;
    float4 acc = { 0.f, 0.f, 0.f, 0.f };
    const float scale = 0.0625f;   // 1/sqrt(256)

    if (beg < end) {
        int e = perm[beg];
        float4 sv = *(const float4*)&scat[(size_t)e * D + lane * 4];
        for (int pos = beg; pos < end; ++pos) {
            float4 cur = sv;
            if (pos + 1 < end) {
                int e2 = perm[pos + 1];
                sv = *(const float4*)&scat[(size_t)e2 * D + lane * 4];
            }
            float d = fmaf(cur.x, wqv.x, fmaf(cur.y, wqv.y,
                      fmaf(cur.z, wqv.z, cur.w * wqv.w)));
            #pragma unroll
            for (int off = 32; off; off >>= 1) d += __shfl_xor(d, off, 64);
            float score = d * scale;
            float nm = fmaxf(m, score);
            float al = __expf(m - nm);       // first iter: exp(-inf)=0
            float p  = __expf(score - nm);
            l = fmaf(l, al, p);
            acc.x = fmaf(acc.x, al, p * cur.x);
            acc.y = fmaf(acc.y, al, p * cur.y);
            acc.z = fmaf(acc.z, al, p * cur.z);
            acc.w = fmaf(acc.w, al, p * cur.w);
            m = nm;
        }
    }
    float inv = 1.f / fmaxf(l, 1e-9f);
    ushort4 o = { f2bf(acc.x * inv), f2bf(acc.y * inv),
                  f2bf(acc.z * inv), f2bf(acc.w * inv) };
    *(ushort4*)&comb[(size_t)n * D + lane * 4] = o;
}

// ---------------------------------------------------------------------------
extern "C" void kernel_launch(void* const* d_in, const int* in_sizes, int n_in,
                              void* d_out, int out_size, void* d_ws, size_t ws_size,
                              hipStream_t stream) {
    const float* scat = (const float*)d_in[0];
    const float* prev = (const float*)d_in[1];
    const float* Wk   = (const float*)d_in[2];
    // d_in[3] = b_k: constant shift within a segment cancels in softmax.
    const float* Wg   = (const float*)d_in[4];
    const float* bg   = (const float*)d_in[5];
    const int*   idx  = (const int*)d_in[6];

    const int E_ = in_sizes[6];
    const int Nn = in_sizes[1] / D;

    float* out = (float*)d_out;

    char* w = (char*)d_ws;
    auto alloc = [&](size_t bytes) -> char* {
        char* p = w;
        w += (bytes + 255) & ~(size_t)255;
        return p;
    };
    unsigned short* prev_bf = (unsigned short*)alloc((size_t)Nn * D * 2);
    unsigned short* wq_bf   = (unsigned short*)alloc((size_t)Nn * D * 2);
    unsigned short* comb_bf = (unsigned short*)alloc((size_t)Nn * D * 2);
    unsigned short* Wk_bf   = (unsigned short*)alloc((size_t)D * D * 2);
    unsigned short* WgT_bf  = (unsigned short*)alloc((size_t)2 * D * D * 2);
    int*   counts    = (int*)alloc((size_t)Nn * 4);
    int*   offsets   = (int*)alloc(((size_t)Nn + 1) * 4);
    int    P         = (Nn + 1023) / 1024;
    int*   chunkSums = (int*)alloc((size_t)P * 4);
    int*   chunkOff  = (int*)alloc((size_t)P * 4);
    int*   rank      = (int*)alloc((size_t)E_ * 4);
    int*   perm      = (int*)alloc((size_t)E_ * 4);

    // 1) conversions
    int n8 = Nn * D / 8;
    k_cvt<<<(n8 + 255) / 256, 256, 0, stream>>>(prev, prev_bf, n8);
    k_cvt<<<(D * D / 8 + 255) / 256, 256, 0, stream>>>(Wk, Wk_bf, D * D / 8);
    k_cvt_wg<<<2 * D, D, 0, stream>>>(Wg, WgT_bf);

    // 2) counting sort of occurrences by node (overlaps with conversions)
    k_zero<<<(Nn + 255) / 256, 256, 0, stream>>>(counts, Nn);
    int gb = (E_ + 255) / 256;
    k_hist<<<gb, 256, 0, stream>>>(idx, counts, rank, E_);
    k_part<<<P, 256, 0, stream>>>(counts, chunkSums, Nn);
    k_top<<<1, 256, 0, stream>>>(chunkSums, chunkOff, P, offsets, Nn, E_);
    k_off<<<P, 256, 0, stream>>>(counts, chunkOff, offsets, Nn);
    k_scatter<<<gb, 256, 0, stream>>>(idx, rank, offsets, perm, E_);

    // 3) wq = prev @ Wk^T  (MFMA; Wk row-major IS the n-major B)
    int gm = (Nn + 63) / 64;
    k_mfma_gemm<256, false><<<gm, 256, 0, stream>>>(
        prev_bf, nullptr, Wk_bf, nullptr, nullptr, wq_bf, nullptr, Nn);

    // 4) per-node online-softmax attention (single pass over scattered_input)
    k_combine<<<(Nn + 3) / 4, 256, 0, stream>>>(scat, wq_bf, offsets, perm, comb_bf, Nn);

    // 5) gate GEMM + sigmoid lerp epilogue (MFMA)
    k_mfma_gemm<512, true><<<gm, 256, 0, stream>>>(
        prev_bf, comb_bf, WgT_bf, bg, prev, nullptr, out, Nn);
}